// Round 15
// baseline (490.507 us; speedup 1.0000x reference)
//
#include <hip/hip_runtime.h>
#include <hip/hip_fp16.h>
#include <stdint.h>

// SymmetricQuantLinear: out[m,n] = scale[n] * sum_k x[m,k] * (nib(k,n) - 8)
//   x: f32 [M][K] (fp16-origin), packed: int32 [K/2][N], scale f32 [N].
//   Out f32 [M][N].
// Round 15: LDS-BW analysis -> 4 waves x (128x128 per wave), 256x256 tile,
//   BK=32. Frag reads/K-tile: 64 KB (was 196), staging 32 KB -> LDS ~900 cy
//   vs MFMA 1242 cy => compute-bound. acc=256 VGPR -> 1 wave/SIMD.
//   3 LDS slots (48 KB), counted WAITV(8) 2-tiles-ahead, progressive bf
//   reads 1 phase ahead w/ counted lgkmcnt, 16-MFMA clusters.
//   XCD-pair mapping (R14-validated, FETCH 403 MB). Prepasses unchanged.

#define M_DIM 4096
#define K_DIM 4096
#define N_DIM 11008
#define KH    (K_DIM / 2)

#define WS_XH_BYTES  ((size_t)M_DIM * K_DIM * 2)            // 32 MiB

typedef __attribute__((ext_vector_type(8))) _Float16 f16x8;
typedef __attribute__((ext_vector_type(2))) _Float16 h2;
typedef __attribute__((ext_vector_type(4))) float f32x4;

__device__ __forceinline__ unsigned pack_f16_pair(float lo, float hi) {
    return __builtin_bit_cast(unsigned, __builtin_amdgcn_cvt_pkrtz(lo, hi));
}

__device__ __forceinline__ unsigned dq_pair(unsigned v) {
    unsigned c = (v & 0xFu) | ((v << 12) & 0x000F0000u) | 0x64006400u;
    h2 r = __builtin_bit_cast(h2, c) + __builtin_bit_cast(h2, 0xE408E408u);
    return __builtin_bit_cast(unsigned, r);
}

__device__ __forceinline__ void gld_lds16(const void* g, void* l) {
    __builtin_amdgcn_global_load_lds(
        (const __attribute__((address_space(1))) unsigned int*)g,
        (__attribute__((address_space(3))) unsigned int*)l,
        16, 0, 0);
}

// ---- Pass 1a: X f32 -> fp16 (exact) ----
__global__ void __launch_bounds__(256) cvt_x_kernel(
    const float* __restrict__ X, unsigned short* __restrict__ Xh)
{
    size_t i = ((size_t)blockIdx.x * 256 + threadIdx.x) * 8;
    float4 a = *(const float4*)(X + i);
    float4 b = *(const float4*)(X + i + 4);
    uint4 o = make_uint4(pack_f16_pair(a.x, a.y), pack_f16_pair(a.z, a.w),
                         pack_f16_pair(b.x, b.y), pack_f16_pair(b.z, b.w));
    *(uint4*)(Xh + i) = o;
}

// ---- Pass 1b: WP [KH][N] -> Wt uint32 [N][KH] ----
__global__ void __launch_bounds__(256) dqt_kernel(
    const int* __restrict__ WP, unsigned* __restrict__ Wt)
{
    __shared__ unsigned Lt[64][65];
    const int t = threadIdx.x;
    const int n0 = blockIdx.x * 64;
    const int r0 = blockIdx.y * 64;
    const int g = t >> 6, l = t & 63;
#pragma unroll
    for (int i = 0; i < 16; ++i) {
        const int r = r0 + g * 16 + i;
        Lt[l][g * 16 + i] = dq_pair((unsigned)WP[(size_t)r * N_DIM + n0 + l]);
    }
    __syncthreads();
    const int nr = t >> 2, sg = t & 3;
    unsigned* dst = Wt + (size_t)(n0 + nr) * KH + r0 + sg * 16;
#pragma unroll
    for (int c = 0; c < 4; ++c) {
        uint4 v = make_uint4(Lt[nr][sg * 16 + c * 4 + 0], Lt[nr][sg * 16 + c * 4 + 1],
                             Lt[nr][sg * 16 + c * 4 + 2], Lt[nr][sg * 16 + c * 4 + 3]);
        *(uint4*)(dst + c * 4) = v;
    }
}

// ---- Pass 2: 4-wave fat-tile fp16 GEMM ----
__global__ void __launch_bounds__(256, 1) qgemm8_kernel(
    const unsigned short* __restrict__ Xh,   // fp16 [M][K]
    const unsigned*       __restrict__ Wt,   // uint32 [N][KH] (fp16 [N][K])
    const float*          __restrict__ WS,   // [N]
    float*                __restrict__ Out)  // f32 [M][N]
{
    __shared__ unsigned short LA[3][256 * 32];   // 16 KB per slot
    __shared__ unsigned short LB[3][256 * 32];   // 96 KB total

    const int t = threadIdx.x;     // 0..255
    const int w = t >> 6;          // wave 0..3
    const int l = t & 63;

    // XCD pairing: xcd owns M-rows {2x,2x+1}, N-major (R14: FETCH 403 MB).
    const int bid = blockIdx.x;                 // 0..687
    const int xcd = bid & 7;
    const int i8  = bid >> 3;                   // 0..85
    const int bx  = i8 >> 1;                    // 0..42
    const int by  = (xcd << 1) | (i8 & 1);      // 0..15
    const int bm0 = by * 256;
    const int bn0 = bx * 256;

    const int wr = w >> 1;         // 0..1 -> rows wr*128
    const int wc = w & 1;          // 0..1 -> cols wc*128

    f32x4 acc[8][8];
#pragma unroll
    for (int i = 0; i < 8; ++i)
#pragma unroll
        for (int j = 0; j < 8; ++j)
            acc[i][j] = (f32x4){0.f, 0.f, 0.f, 0.f};

    // ---- staging (source-pre-swizzled; LDS dest linear; R10 swizzle) ----
    const int r0 = t >> 2;         // 0..63
    const int c0 = t & 3;
    const int cS = c0 ^ ((r0 >> 1) & 3);       // 64 = 0 mod 8 -> same all j
    const unsigned short* gA = Xh + (size_t)(bm0 + r0) * K_DIM + cS * 8;
    const unsigned*       gB = Wt + (size_t)(bn0 + r0) * KH + cS * 4;
    const int t8 = t * 8;          // = r0*32 + c0*8

#define SA(s, kt, j) gld_lds16(gA + (size_t)(64 * (j)) * K_DIM + (size_t)(kt) * 32, \
                               &LA[s][(j) * 2048 + t8])
#define SBW(s, kt, j) gld_lds16(gB + (size_t)(64 * (j)) * KH + (size_t)(kt) * 16,   \
                                &LB[s][(j) * 2048 + t8])

    const int lq = l >> 4;
    const int lr = l & 15;

    f16x8 af[8], bf[8];

#define RAF(s) do {                                                           \
    _Pragma("unroll")                                                         \
    for (int mi = 0; mi < 8; ++mi) {                                          \
        const int row = wr * 128 + mi * 16 + lr;                              \
        af[mi] = *(const f16x8*)&LA[s][row * 32 + ((lq ^ ((row >> 1) & 3)) * 8)]; \
    }                                                                         \
} while (0)

#define RBF(s, ni) do {                                                       \
    const int row = wc * 128 + (ni) * 16 + lr;                                \
    bf[ni] = *(const f16x8*)&LB[s][row * 32 + ((lq ^ ((row >> 1) & 3)) * 8)]; \
} while (0)

#define MFMA2(n0_, n1_) do {                                                  \
    _Pragma("unroll")                                                         \
    for (int mi = 0; mi < 8; ++mi)                                            \
        acc[mi][n0_] = __builtin_amdgcn_mfma_f32_16x16x32_f16(                \
            af[mi], bf[n0_], acc[mi][n0_], 0, 0, 0);                          \
    _Pragma("unroll")                                                         \
    for (int mi = 0; mi < 8; ++mi)                                            \
        acc[mi][n1_] = __builtin_amdgcn_mfma_f32_16x16x32_f16(                \
            af[mi], bf[n1_], acc[mi][n1_], 0, 0, 0);                          \
} while (0)

#define WAITV(n)  asm volatile("s_waitcnt vmcnt(" #n ")" ::: "memory")
#define LGKM(n)   do { asm volatile("s_waitcnt lgkmcnt(" #n ")" ::: "memory"); \
                       __builtin_amdgcn_sched_barrier(0); } while (0)
#define BAR()     __builtin_amdgcn_s_barrier()

    // One K-tile: s = slot of this tile; sn/ktn = staging target (2 ahead)
#define TILE_F(s, sn, ktn) do {                                               \
    WAITV(8); BAR();                                                          \
    RAF(s); RBF(s, 0); RBF(s, 1);          /* 10 ds_read */                   \
    RBF(s, 2); RBF(s, 3); SA(sn, ktn, 0); SA(sn, ktn, 1);                     \
    LGKM(2); MFMA2(0, 1);                                                     \
    RBF(s, 4); RBF(s, 5); SA(sn, ktn, 2); SA(sn, ktn, 3);                     \
    LGKM(2); MFMA2(2, 3);                                                     \
    RBF(s, 6); RBF(s, 7); SBW(sn, ktn, 0); SBW(sn, ktn, 1);                   \
    LGKM(2); MFMA2(4, 5);                                                     \
    SBW(sn, ktn, 2); SBW(sn, ktn, 3);                                         \
    LGKM(0); MFMA2(6, 7);                                                     \
} while (0)

#define TILE_P(s) do {                     /* no staging, not last */         \
    WAITV(8); BAR();                                                          \
    RAF(s); RBF(s, 0); RBF(s, 1);                                             \
    RBF(s, 2); RBF(s, 3); LGKM(2); MFMA2(0, 1);                               \
    RBF(s, 4); RBF(s, 5); LGKM(2); MFMA2(2, 3);                               \
    RBF(s, 6); RBF(s, 7); LGKM(2); MFMA2(4, 5);                               \
    LGKM(0); MFMA2(6, 7);                                                     \
} while (0)

#define TILE_L(s) do {                     /* last tile */                    \
    WAITV(0); BAR();                                                          \
    RAF(s); RBF(s, 0); RBF(s, 1);                                             \
    RBF(s, 2); RBF(s, 3); LGKM(2); MFMA2(0, 1);                               \
    RBF(s, 4); RBF(s, 5); LGKM(2); MFMA2(2, 3);                               \
    RBF(s, 6); RBF(s, 7); LGKM(2); MFMA2(4, 5);                               \
    LGKM(0); MFMA2(6, 7);                                                     \
} while (0)

    // prologue: tiles 0,1 -> slots 0,1 (16 loads in flight)
    SA(0, 0, 0); SA(0, 0, 1); SA(0, 0, 2); SA(0, 0, 3);
    SBW(0, 0, 0); SBW(0, 0, 1); SBW(0, 0, 2); SBW(0, 0, 3);
    SA(1, 1, 0); SA(1, 1, 1); SA(1, 1, 2); SA(1, 1, 3);
    SBW(1, 1, 0); SBW(1, 1, 1); SBW(1, 1, 2); SBW(1, 1, 3);

    // main loop: 126 tiles (42 x 3), staging 2 ahead; slots static
    for (int i = 0; i < 42; ++i) {
        TILE_F(0, 2, 3 * i + 2);
        TILE_F(1, 0, 3 * i + 3);
        TILE_F(2, 1, 3 * i + 4);
    }
    TILE_P(0);                             // tile 126
    TILE_L(1);                             // tile 127

    // epilogue: per-column scale, f32 store
#pragma unroll
    for (int ni = 0; ni < 8; ++ni) {
        const int col = bn0 + wc * 128 + ni * 16 + lr;
        const float s = WS[col];
#pragma unroll
        for (int mi = 0; mi < 8; ++mi) {
            const int row = bm0 + wr * 128 + mi * 16 + lq * 4;
#pragma unroll
            for (int i = 0; i < 4; ++i) {
                Out[(size_t)(row + i) * N_DIM + col] = acc[mi][ni][i] * s;
            }
        }
    }
#undef SA
#undef SBW
#undef RAF
#undef RBF
#undef MFMA2
#undef WAITV
#undef LGKM
#undef BAR
#undef TILE_F
#undef TILE_P
#undef TILE_L
}

extern "C" void kernel_launch(void* const* d_in, const int* in_sizes, int n_in,
                              void* d_out, int out_size, void* d_ws, size_t ws_size,
                              hipStream_t stream) {
    const float* X  = (const float*)d_in[0];
    const int*   WP = (const int*)d_in[1];
    const float* WS = (const float*)d_in[2];
    float*       Out = (float*)d_out;

    unsigned short* Xh = (unsigned short*)d_ws;
    unsigned*       Wt = (unsigned*)((char*)d_ws + WS_XH_BYTES);

    cvt_x_kernel<<<(M_DIM * K_DIM) / (256 * 8), 256, 0, stream>>>(X, Xh);
    dim3 gdq(N_DIM / 64, KH / 64);                    // 172 x 32
    dqt_kernel<<<gdq, 256, 0, stream>>>(WP, Wt);
    dim3 grid((N_DIM / 256) * (M_DIM / 256));         // 688
    qgemm8_kernel<<<grid, 256, 0, stream>>>(Xh, Wt, WS, Out);
}

// Round 16
// 409.388 us; speedup vs baseline: 1.1981x; 1.1981x over previous
//
#include <hip/hip_runtime.h>
#include <hip/hip_fp16.h>
#include <stdint.h>

// SymmetricQuantLinear: out[m,n] = scale[n] * sum_k x[m,k] * (nib(k,n) - 8)
// Round 16: counted-queue 8-phase GEMM. 256x256, BK=64, 8 waves, 2 dbufs.
//   8 staging units/tile (8KB = 1 gld_lds/thread), issued in consumption
//   order; WAITV(4)@ph1 + WAITV(6)@ph3 drain only >=2.5-phase-old loads;
//   2 barriers/tile. Frags 64 VGPR; acc 128 AGPR -> 2 waves/SIMD.

#define M_DIM 4096
#define K_DIM 4096
#define N_DIM 11008
#define KH    (K_DIM / 2)

#define WS_XH_BYTES  ((size_t)M_DIM * K_DIM * 2)            // 32 MiB

typedef __attribute__((ext_vector_type(8))) _Float16 f16x8;
typedef __attribute__((ext_vector_type(2))) _Float16 h2;
typedef __attribute__((ext_vector_type(4))) float f32x4;

__device__ __forceinline__ unsigned pack_f16_pair(float lo, float hi) {
    return __builtin_bit_cast(unsigned, __builtin_amdgcn_cvt_pkrtz(lo, hi));
}

__device__ __forceinline__ unsigned dq_pair(unsigned v) {
    unsigned c = (v & 0xFu) | ((v << 12) & 0x000F0000u) | 0x64006400u;
    h2 r = __builtin_bit_cast(h2, c) + __builtin_bit_cast(h2, 0xE408E408u);
    return __builtin_bit_cast(unsigned, r);
}

__device__ __forceinline__ void gld_lds16(const void* g, void* l) {
    __builtin_amdgcn_global_load_lds(
        (const __attribute__((address_space(1))) unsigned int*)g,
        (__attribute__((address_space(3))) unsigned int*)l,
        16, 0, 0);
}

// ---- Pass 1a: X f32 -> fp16 (exact) ----
__global__ void __launch_bounds__(256) cvt_x_kernel(
    const float* __restrict__ X, unsigned short* __restrict__ Xh)
{
    size_t i = ((size_t)blockIdx.x * 256 + threadIdx.x) * 8;
    float4 a = *(const float4*)(X + i);
    float4 b = *(const float4*)(X + i + 4);
    uint4 o = make_uint4(pack_f16_pair(a.x, a.y), pack_f16_pair(a.z, a.w),
                         pack_f16_pair(b.x, b.y), pack_f16_pair(b.z, b.w));
    *(uint4*)(Xh + i) = o;
}

// ---- Pass 1b: WP [KH][N] -> Wt uint32 [N][KH] ----
__global__ void __launch_bounds__(256) dqt_kernel(
    const int* __restrict__ WP, unsigned* __restrict__ Wt)
{
    __shared__ unsigned Lt[64][65];
    const int t = threadIdx.x;
    const int n0 = blockIdx.x * 64;
    const int r0 = blockIdx.y * 64;
    const int g = t >> 6, l = t & 63;
#pragma unroll
    for (int i = 0; i < 16; ++i) {
        const int r = r0 + g * 16 + i;
        Lt[l][g * 16 + i] = dq_pair((unsigned)WP[(size_t)r * N_DIM + n0 + l]);
    }
    __syncthreads();
    const int nr = t >> 2, sg = t & 3;
    unsigned* dst = Wt + (size_t)(n0 + nr) * KH + r0 + sg * 16;
#pragma unroll
    for (int c = 0; c < 4; ++c) {
        uint4 v = make_uint4(Lt[nr][sg * 16 + c * 4 + 0], Lt[nr][sg * 16 + c * 4 + 1],
                             Lt[nr][sg * 16 + c * 4 + 2], Lt[nr][sg * 16 + c * 4 + 3]);
        *(uint4*)(dst + c * 4) = v;
    }
}

// ---- Pass 2: counted-queue 8-phase fp16 GEMM ----
__global__ void __launch_bounds__(512, 2) qgemm9_kernel(
    const unsigned short* __restrict__ Xh,   // fp16 [M][K]
    const unsigned*       __restrict__ Wt,   // uint32 [N][KH] (fp16 [N][K])
    const float*          __restrict__ WS,   // [N]
    float*                __restrict__ Out)  // f32 [M][N]
{
    __shared__ unsigned short LA[2][2][8192];   // [dbuf][half][128 x 64]
    __shared__ unsigned short LB[2][2][8192];   // 128 KB total

    const int t = threadIdx.x;     // 0..511
    const int w = t >> 6;          // wave 0..7
    const int l = t & 63;

    // XCD pairing: xcd owns M-rows {2x,2x+1}, N-major (R14: FETCH 403 MB).
    const int bid = blockIdx.x;                 // 0..687
    const int xcd = bid & 7;
    const int i8  = bid >> 3;                   // 0..85
    const int bx  = i8 >> 1;                    // 0..42
    const int by  = (xcd << 1) | (i8 & 1);      // 0..15
    const int bm0 = by * 256;
    const int bn0 = bx * 256;

    const int wr = w >> 2;         // A half
    const int wc = w & 3;          // B: half = wc>>1, sub = wc&1

    f32x4 acc[8][4];
#pragma unroll
    for (int i = 0; i < 8; ++i)
#pragma unroll
        for (int j = 0; j < 4; ++j)
            acc[i][j] = (f32x4){0.f, 0.f, 0.f, 0.f};

    // staging: unit = 64 rows x 64 ushort = 8 KB = 512 threads x 16 B.
    // thread covers row (t>>3), 16B slot (t&7); source slot XOR-swizzled.
    const int cS = (t & 7) ^ ((t >> 3) & 7);
    const unsigned short* gA = Xh + (size_t)(bm0 + (t >> 3)) * K_DIM + cS * 8;
    const unsigned*       gB = Wt + (size_t)(bn0 + (t >> 3)) * KH + cS * 4;
    const int t8 = t * 8;

#define SU_A(buf, h, c, kt)                                                   \
    gld_lds16(gA + (size_t)((h) * 128 + (c) * 64) * K_DIM + (size_t)(kt) * 64, \
              &LA[buf][h][(c) * 4096 + t8])
#define SU_B(buf, bh, ch, kt)                                                 \
    gld_lds16(gB + (size_t)((bh) * 128 + (ch) * 64) * KH + (size_t)(kt) * 32, \
              &LB[buf][bh][(ch) * 4096 + t8])

    const int lq = l >> 4;
    const int lr = l & 15;

    f16x8 af0[4][2], af1[4][2], bf0[2][2], bf1[2][2];

#define READ_AF(D, h, ARR) do {                                               \
    _Pragma("unroll")                                                         \
    for (int mi = 0; mi < 4; ++mi) {                                          \
        const int lrow = (h) * 64 + mi * 16 + lr;                             \
        _Pragma("unroll")                                                     \
        for (int ks = 0; ks < 2; ++ks)                                        \
            ARR[mi][ks] = *(const f16x8*)                                     \
                &LA[D][wr][lrow * 64 + (((ks * 4 + lq) ^ (lrow & 7)) * 8)];   \
    }                                                                         \
} while (0)

#define READ_BF(D, ch, ARR) do {                                              \
    _Pragma("unroll")                                                         \
    for (int n = 0; n < 2; ++n) {                                             \
        const int lrow = (wc & 1) * 64 + (ch) * 32 + n * 16 + lr;             \
        _Pragma("unroll")                                                     \
        for (int ks = 0; ks < 2; ++ks)                                        \
            ARR[n][ks] = *(const f16x8*)                                      \
                &LB[D][wc >> 1][lrow * 64 + (((ks * 4 + lq) ^ (lrow & 7)) * 8)]; \
    }                                                                         \
} while (0)

    // 16 MFMA cluster: ks outer (dependency distance 8)
#define Q16(MB, AF, BF, NB) do {                                              \
    __builtin_amdgcn_s_setprio(1);                                            \
    _Pragma("unroll")                                                         \
    for (int ks = 0; ks < 2; ++ks)                                            \
        _Pragma("unroll")                                                     \
        for (int mi = 0; mi < 4; ++mi)                                        \
            _Pragma("unroll")                                                 \
            for (int n = 0; n < 2; ++n)                                       \
                acc[(MB) + mi][(NB) + n] =                                    \
                    __builtin_amdgcn_mfma_f32_16x16x32_f16(                   \
                        AF[mi][ks], BF[n][ks], acc[(MB) + mi][(NB) + n],      \
                        0, 0, 0);                                             \
    __builtin_amdgcn_s_setprio(0);                                            \
} while (0)

#define WAITV(n) asm volatile("s_waitcnt vmcnt(" #n ")" ::: "memory")
#define LGKM0()  do { asm volatile("s_waitcnt lgkmcnt(0)" ::: "memory");      \
                      __builtin_amdgcn_sched_barrier(0); } while (0)
#define BAR()    __builtin_amdgcn_s_barrier()

    // process tile (dbuf D), stage tile ktn into DN. 2 barriers, 2 vmcnts.
#define TILE_STD(D, DN, ktn) do {                                             \
    SU_B(DN, 0, 0, ktn); SU_B(DN, 0, 1, ktn);                                 \
    WAITV(4); BAR();                                                          \
    READ_AF(D, 0, af0); READ_BF(D, 0, bf0); LGKM0();                          \
    Q16(0, af0, bf0, 0);                                                      \
    SU_B(DN, 1, 0, ktn); SU_B(DN, 1, 1, ktn);                                 \
    READ_BF(D, 1, bf1); LGKM0();                                              \
    Q16(0, af0, bf1, 2);                                                      \
    SU_A(DN, 0, 0, ktn); SU_A(DN, 1, 0, ktn);                                 \
    WAITV(6); BAR();                                                          \
    READ_AF(D, 1, af1); LGKM0();                                              \
    Q16(4, af1, bf1, 2);                                                      \
    SU_A(DN, 0, 1, ktn); SU_A(DN, 1, 1, ktn);                                 \
    Q16(4, af1, bf0, 0);                                                      \
} while (0)

#define TILE_LAST(D) do {                                                     \
    WAITV(2); BAR();                                                          \
    READ_AF(D, 0, af0); READ_BF(D, 0, bf0); LGKM0();                          \
    Q16(0, af0, bf0, 0);                                                      \
    READ_BF(D, 1, bf1); LGKM0();                                              \
    Q16(0, af0, bf1, 2);                                                      \
    WAITV(0); BAR();                                                          \
    READ_AF(D, 1, af1); LGKM0();                                              \
    Q16(4, af1, bf1, 2);                                                      \
    Q16(4, af1, bf0, 0);                                                      \
} while (0)

    // prologue: tile 0 units in consumption order
    SU_B(0, 0, 0, 0); SU_B(0, 0, 1, 0); SU_B(0, 1, 0, 0); SU_B(0, 1, 1, 0);
    SU_A(0, 0, 0, 0); SU_A(0, 1, 0, 0); SU_A(0, 0, 1, 0); SU_A(0, 1, 1, 0);

    for (int i = 0; i < 31; ++i) {
        TILE_STD(0, 1, 2 * i + 1);        // tile 2i,   stages 2i+1
        TILE_STD(1, 0, 2 * i + 2);        // tile 2i+1, stages 2i+2
    }
    TILE_STD(0, 1, 63);                   // tile 62, stages 63
    TILE_LAST(1);                         // tile 63

    // epilogue: per-column scale, f32 store
#pragma unroll
    for (int ni = 0; ni < 4; ++ni) {
        const int col = bn0 + wc * 64 + ni * 16 + lr;
        const float s = WS[col];
#pragma unroll
        for (int mi = 0; mi < 8; ++mi) {
            const int row = bm0 + wr * 128 + mi * 16 + lq * 4;
#pragma unroll
            for (int i = 0; i < 4; ++i) {
                Out[(size_t)(row + i) * N_DIM + col] = acc[mi][ni][i] * s;
            }
        }
    }
#undef SU_A
#undef SU_B
#undef READ_AF
#undef READ_BF
#undef Q16
#undef WAITV
#undef LGKM0
#undef BAR
#undef TILE_STD
#undef TILE_LAST
}

extern "C" void kernel_launch(void* const* d_in, const int* in_sizes, int n_in,
                              void* d_out, int out_size, void* d_ws, size_t ws_size,
                              hipStream_t stream) {
    const float* X  = (const float*)d_in[0];
    const int*   WP = (const int*)d_in[1];
    const float* WS = (const float*)d_in[2];
    float*       Out = (float*)d_out;

    unsigned short* Xh = (unsigned short*)d_ws;
    unsigned*       Wt = (unsigned*)((char*)d_ws + WS_XH_BYTES);

    cvt_x_kernel<<<(M_DIM * K_DIM) / (256 * 8), 256, 0, stream>>>(X, Xh);
    dim3 gdq(N_DIM / 64, KH / 64);                    // 172 x 32
    dqt_kernel<<<gdq, 256, 0, stream>>>(WP, Wt);
    dim3 grid((N_DIM / 256) * (M_DIM / 256));         // 688
    qgemm9_kernel<<<grid, 512, 0, stream>>>(Xh, Wt, WS, Out);
}